// Round 3
// baseline (302.377 us; speedup 1.0000x reference)
//
#include <hip/hip_runtime.h>

// bpd_cuda: super-BPD boundary angle diff, 512x512.
// R3: stripe-hierarchical min-label CC (full-width stripes -> no vertical seams).
//   k_local   : per 512x32 stripe (64KB LDS): compute pf (angle-bin parent) for the
//               stripe, then LDS union-find over ALL intra-stripe edges, publish
//               depth-1 global par.
//   k_global  : unions over stripe-crossing edges only (~15K boundary pixels).
//   k_flatten : labels = find(t); c3 = pf^3.
//   k_output  : wrapped |ang[c3[i]] - ang[c3[n]]| for right/down where labels differ.
// All par mutations are atomicMin -> monotone decreasing, benign races.
// Converged root per component == min flat index == FastSV converged label.

static constexpr double PI_D = 3.14159265;
#define LDSN 16384   // ints of LDS union-find per block (64 KB)

__device__ __constant__ int c_DH[8] = {1, 1, 0, -1, -1, -1, 0, 1};
__device__ __constant__ int c_DW[8] = {0, 1, 1, 1, 0, -1, -1, -1};

// static fallback scratch (4 int arrays for N<=512*512) in case ws_size is small
__device__ int g_fb[4 * 262144];

// find with path-halving; all writes via atomicMin (monotone, benign races)
__device__ __forceinline__ int uf_find(int x, int* par) {
    while (true) {
        int p = par[x];
        if (p == x) return x;
        int gp = par[p];
        if (gp == p) return p;
        atomicMin(&par[x], gp);
        x = gp;
    }
}

// lock-free min-hooking union: always hook larger root under smaller
__device__ __forceinline__ void uf_unite(int u, int v, int* par) {
    int ru = uf_find(u, par);
    int rv = uf_find(v, par);
    while (ru != rv) {
        if (ru > rv) { int t = ru; ru = rv; rv = t; }   // ru < rv
        int old = atomicMin(&par[rv], ru);
        if (old == rv) return;        // rv was a root: linked, done
        rv = uf_find(old, par);       // rv was hooked meanwhile; keep merging
        ru = uf_find(ru, par);
    }
}

// per-pixel parent from the angle field (bit-exact vs the JAX f32 reference)
__device__ __forceinline__ int parent_of(const float* __restrict__ ang,
                                         int t, int i, int j, int H, int W, float thr) {
    const float a = ang[t];
    const float a8 = (float)(PI_D / 8.0);
    const float a4 = (float)(PI_D / 4.0);
    float posf = rintf((a + a8) / a4);        // jnp.round == round-half-even == rintf
    if (posf >= 8.0f) posf -= 8.0f;
    const int pos = (int)posf;
    const int nh = i + c_DH[pos];
    const int nw = j + c_DW[pos];
    const bool inb = (nh >= 0) & (nh < H) & (nw >= 0) & (nw < W);
    const int nhc = min(max(nh, 0), H - 1);
    const int nwc = min(max(nw, 0), W - 1);
    float ad = fabsf(a - ang[nhc * W + nwc]);
    const float twopi = (float)(2.0 * PI_D);
    ad = fminf(ad, twopi - ad);
    const bool is_root = (!inb) || (ad > thr);
    return is_root ? t : (nhc * W + nwc);
}

// one full-width stripe per block: compute pf, LDS union-find, publish par
__global__ void k_local(const float* __restrict__ ang,
                        const int* __restrict__ hp, const int* __restrict__ wp,
                        const int* __restrict__ tap,
                        int N, int* __restrict__ pf, int* __restrict__ par) {
    const int H = hp[0], W = wp[0];
    const float thr = (float)((double)tap[0] * PI_D / 180.0);
    const int SH = max(1, LDSN / W);                 // stripe height (32 for W=512)
    const int nstripes = (H + SH - 1) / SH;
    __shared__ int lpar[LDSN];
    for (int s = blockIdx.x; s < nstripes; s += gridDim.x) {
        const int r0 = s * SH;                       // first row of stripe
        const int base = r0 * W;                     // flat index of stripe start
        const int npx = min(SH, H - r0) * W;
        // phase 0: init LDS forest + compute pf for the stripe
        for (int lp = threadIdx.x; lp < npx; lp += blockDim.x) lpar[lp] = lp;
        for (int lp = threadIdx.x; lp < npx; lp += blockDim.x) {
            const int g = base + lp;
            const int i = r0 + lp / W, j = lp % W;
            pf[g] = parent_of(ang, g, i, j, H, W, thr);
        }
        __syncthreads();   // pf visible block-wide (same CU)
        // phase 1: intra-stripe unions (parent edges + root-window edges)
        for (int lp = threadIdx.x; lp < npx; lp += blockDim.x) {
            const int g = base + lp;
            const int p = pf[g];
            if (p != g) {
                if (p >= base && p < base + npx) uf_unite(lp, p - base, lpar);
            } else {
                // root: window dh in [0,2], dw in [-3,2], neighbor root, in [0,H-2]x[0,W-2]
                const int i = r0 + lp / W, j = lp % W;
                for (int dh = 0; dh <= 2; ++dh) {
                    const int nh = i + dh;
                    if (nh > H - 2) break;
                    const int nl = (nh - r0) * W;
                    if (nl >= npx) break;            // next stripe: handled in k_global
                    for (int dw = -3; dw <= 2; ++dw) {
                        if (dh == 0 && dw == 0) continue;
                        const int nw = j + dw;
                        if ((unsigned)nw > (unsigned)(W - 2)) continue;
                        const int n = nh * W + nw;
                        if (pf[n] == n) uf_unite(lp, nl + nw, lpar);
                    }
                }
            }
        }
        __syncthreads();
        // phase 2: publish depth-1 global forest
        for (int lp = threadIdx.x; lp < npx; lp += blockDim.x) {
            const int lr = uf_find(lp, lpar);
            par[base + lp] = base + lr;
        }
        __syncthreads();   // before re-init for next stripe
    }
}

// unions over stripe-crossing edges only
__global__ void k_global(const int* __restrict__ pf,
                         const int* __restrict__ hp, const int* __restrict__ wp,
                         int N, int* par) {
    int t = blockIdx.x * blockDim.x + threadIdx.x;
    if (t >= N) return;
    const int H = hp[0], W = wp[0];
    const int SH = max(1, LDSN / W);
    const int i = t / W, j = t - i * W;
    const int si = i / SH;
    const int p = pf[t];
    if (p != t) {
        if ((p / W) / SH != si) uf_unite(t, p, par);
        return;
    }
    for (int dh = 1; dh <= 2; ++dh) {               // dh=0 never crosses a stripe
        const int nh = i + dh;
        if (nh > H - 2) break;
        if (nh / SH == si) continue;                // same stripe: handled locally
        for (int dw = -3; dw <= 2; ++dw) {
            const int nw = j + dw;
            if ((unsigned)nw > (unsigned)(W - 2)) continue;
            const int n = nh * W + nw;
            if (pf[n] == n) uf_unite(t, n, par);
        }
    }
}

__global__ void k_flatten(const int* __restrict__ pf, int N,
                          int* par, int* __restrict__ labels, int* __restrict__ c3) {
    int t = blockIdx.x * blockDim.x + threadIdx.x;
    if (t >= N) return;
    labels[t] = uf_find(t, par);   // converged root = min index in component
    int p = pf[t];
    p = pf[p];
    p = pf[p];
    c3[t] = p;
}

__global__ void k_output(const float* __restrict__ ang,
                         const int* __restrict__ labels, const int* __restrict__ c3,
                         const int* __restrict__ hp, const int* __restrict__ wp,
                         int N, float* __restrict__ out) {
    int t = blockIdx.x * blockDim.x + threadIdx.x;
    if (t >= N) return;
    const int H = hp[0], W = wp[0];
    const int i = t / W, j = t - i * W;
    const float twopi = (float)(2.0 * PI_D);
    const int l = labels[t];
    const float ac = ang[c3[t]];
    float r0 = 0.0f, r1 = 0.0f;
    if (j + 1 < W) {                      // right neighbor
        const int nidx = t + 1;
        if (labels[nidx] != l) {
            float ad = fabsf(ac - ang[c3[nidx]]);
            r0 = fminf(ad, twopi - ad);
        }
    }
    if (i + 1 < H) {                      // down neighbor
        const int nidx = t + W;
        if (labels[nidx] != l) {
            float ad = fabsf(ac - ang[c3[nidx]]);
            r1 = fminf(ad, twopi - ad);
        }
    }
    reinterpret_cast<float2*>(out)[t] = make_float2(r0, r1);
}

extern "C" void kernel_launch(void* const* d_in, const int* in_sizes, int n_in,
                              void* d_out, int out_size, void* d_ws, size_t ws_size,
                              hipStream_t stream) {
    const float* ang = (const float*)d_in[0];
    const int* hp  = (const int*)d_in[1];
    const int* wp  = (const int*)d_in[2];
    const int* tap = (const int*)d_in[3];
    const int N = in_sizes[0];

    int* base = (int*)d_ws;
    if (ws_size < (size_t)4 * (size_t)N * sizeof(int) && N <= 262144) {
        void* p = nullptr;
        hipGetSymbolAddress(&p, HIP_SYMBOL(g_fb));   // host-side query; capture-safe
        base = (int*)p;
    }
    int* pf     = base;
    int* par    = base + N;
    int* labels = base + 2 * N;
    int* c3     = base + 3 * N;

    const int threads = 256;
    const int blocks = (N + threads - 1) / threads;
    k_local  <<<32, 1024, 0, stream>>>(ang, hp, wp, tap, N, pf, par);
    k_global <<<blocks, threads, 0, stream>>>(pf, hp, wp, N, par);
    k_flatten<<<blocks, threads, 0, stream>>>(pf, N, par, labels, c3);
    k_output <<<blocks, threads, 0, stream>>>(ang, labels, c3, hp, wp, N, (float*)d_out);
}